// Round 5
// baseline (475.863 us; speedup 1.0000x reference)
//
#include <hip/hip_runtime.h>

// LocalAttention: B=4, L=4096, D=1024, H=16, hd=64, WINDOW=128, nW=32
#define M_TOK 16384
#define DM    1024

typedef __bf16 bf16x8 __attribute__((ext_vector_type(8)));
typedef float  f32x4  __attribute__((ext_vector_type(4)));
typedef unsigned short us8 __attribute__((ext_vector_type(8)));
typedef unsigned short us4 __attribute__((ext_vector_type(4)));

__device__ __forceinline__ unsigned short f2bf(float f) {
    unsigned u = __float_as_uint(f);
    u += 0x7FFFu + ((u >> 16) & 1u);   // RNE
    return (unsigned short)(u >> 16);
}

__device__ __forceinline__ void gl2lds16(const unsigned short* g, unsigned short* l) {
    __builtin_amdgcn_global_load_lds(
        (const __attribute__((address_space(1))) unsigned int*)g,
        (__attribute__((address_space(3))) unsigned int*)l, 16, 0, 0);
}

// ---------------------------------------------------------------------------
// fp32 -> bf16 stream convert, 8 elems/thread
// ---------------------------------------------------------------------------
__global__ __launch_bounds__(256) void conv_f2b(
    const float* __restrict__ src, unsigned short* __restrict__ dst, int n8)
{
    int i = blockIdx.x * blockDim.x + threadIdx.x;
    int stride = gridDim.x * blockDim.x;
    for (; i < n8; i += stride) {
        const float4* s = (const float4*)(src + (size_t)i * 8);
        float4 a = s[0], b = s[1];
        us8 o;
        o[0] = f2bf(a.x); o[1] = f2bf(a.y); o[2] = f2bf(a.z); o[3] = f2bf(a.w);
        o[4] = f2bf(b.x); o[5] = f2bf(b.y); o[6] = f2bf(b.z); o[7] = f2bf(b.w);
        *(us8*)(dst + (size_t)i * 8) = o;
    }
}

// ---------------------------------------------------------------------------
// R4 (kept verbatim, verified): 256x256-tile bf16 NT-GEMM, 512 thr, K split
// into 32 k-halves. LDS = 4-slot ring per matrix (128KB). Stage-issue INSIDE
// the compute phase; counted vmcnt(4); never vmcnt(0) until tail.
// ---------------------------------------------------------------------------
#define STAGE_HALF(x_)                                                       \
    {                                                                        \
        const int s_ = ((x_) & 3) * 8192;                                    \
        _Pragma("unroll")                                                    \
        for (int j = 0; j < 2; ++j) {                                        \
            int p = tid + j * 512;                                           \
            int r = p >> 2, cp = p & 3;                                      \
            int cl = cp ^ ((r >> 1) & 3);                                    \
            gl2lds16(Ab + (size_t)r * DM + (x_) * 32 + cl * 8,               \
                     LA + s_ + p * 8);                                       \
            gl2lds16(Bb + (size_t)r * DM + (x_) * 32 + cl * 8,               \
                     LB + s_ + p * 8);                                       \
        }                                                                    \
    }

#define GEMM256_CORE(A_, B_)                                                 \
    __shared__ unsigned short smem[65536]; /* 128 KB */                      \
    const int tid = threadIdx.x, lane = tid & 63, wv = tid >> 6;             \
    const int wm = wv >> 2, wn = wv & 3;                                     \
    const int lrow = lane & 15, qd = lane >> 4;                              \
    const int orig = blockIdx.y * 4 + blockIdx.x;  /* grid (4,64) = 256 */   \
    const int swz  = (orig & 7) * 32 + (orig >> 3);                          \
    const int mbase = (swz >> 2) * 256, nbase = (swz & 3) * 256;             \
    const unsigned short* Ab = (A_) + (size_t)mbase * DM;                    \
    const unsigned short* Bb = (B_) + (size_t)nbase * DM;                    \
    unsigned short* LA = smem;                                               \
    unsigned short* LB = smem + 32768;                                       \
    const int fsw  = (qd ^ ((lrow >> 1) & 3)) * 8;                           \
    const int aoff = (wm * 128 + lrow) * 32 + fsw;                           \
    const int boff = (wn * 64 + lrow) * 32 + fsw;                            \
    f32x4 acc[8][4] = {};                                                    \
    STAGE_HALF(0)                                                            \
    STAGE_HALF(1)                                                            \
    asm volatile("s_waitcnt vmcnt(4)" ::: "memory");                         \
    __builtin_amdgcn_s_barrier();                                            \
    __builtin_amdgcn_sched_barrier(0);                                       \
    _Pragma("unroll 4")                                                      \
    for (int kh = 0; kh < 32; ++kh) {                                        \
        if (kh < 30) STAGE_HALF(kh + 2)                                      \
        const int sb = (kh & 3) * 8192;                                      \
        bf16x8 af[8], bb[4];                                                 \
        _Pragma("unroll")                                                    \
        for (int mi = 0; mi < 8; ++mi)                                       \
            af[mi] = *(const bf16x8*)(LA + sb + aoff + mi * 512);            \
        _Pragma("unroll")                                                    \
        for (int ni = 0; ni < 4; ++ni)                                       \
            bb[ni] = *(const bf16x8*)(LB + sb + boff + ni * 512);            \
        __builtin_amdgcn_s_setprio(1);                                       \
        _Pragma("unroll")                                                    \
        for (int mi = 0; mi < 8; ++mi)                                       \
            _Pragma("unroll")                                                \
            for (int ni = 0; ni < 4; ++ni)                                   \
                acc[mi][ni] = __builtin_amdgcn_mfma_f32_16x16x32_bf16(       \
                    af[mi], bb[ni], acc[mi][ni], 0, 0, 0);                   \
        __builtin_amdgcn_s_setprio(0);                                       \
        if (kh < 30) { asm volatile("s_waitcnt vmcnt(4)" ::: "memory"); }    \
        else         { asm volatile("s_waitcnt vmcnt(0)" ::: "memory"); }    \
        __builtin_amdgcn_s_barrier();                                        \
        __builtin_amdgcn_sched_barrier(0);                                   \
    }

// GEMM producing attention-friendly layouts:
// z=0/1: C[((b*16+h)*4096 + tok)*64 + dh]   (per-head row-major Q/K)
// z=2  : C[((b*16+h)*64 + dh)*4096 + tok]   (per-head TRANSPOSED V)
__global__ __launch_bounds__(512, 2) void gemm256_qkv(
    const unsigned short* __restrict__ A, const unsigned short* __restrict__ W,
    const float* __restrict__ bias, unsigned short* __restrict__ C, int z)
{
    GEMM256_CORE(A, W)
    if (z <= 1) {
        #pragma unroll
        for (int ni = 0; ni < 4; ++ni) {
            int gc = nbase + wn * 64 + ni * 16 + lrow;
            int h = gc >> 6, dh = gc & 63;
            float bv = bias[gc];
            #pragma unroll
            for (int mi = 0; mi < 8; ++mi) {
                int gr0 = mbase + wm * 128 + mi * 16 + qd * 4;
                int b = gr0 >> 12;
                #pragma unroll
                for (int r = 0; r < 4; ++r) {
                    int tok = (gr0 + r) & 4095;
                    C[(((size_t)b * 16 + h) * 4096 + tok) * 64 + dh] =
                        f2bf(acc[mi][ni][r] + bv);
                }
            }
        }
    } else {
        #pragma unroll
        for (int ni = 0; ni < 4; ++ni) {
            int gc = nbase + wn * 64 + ni * 16 + lrow;
            int h = gc >> 6, dh = gc & 63;
            float bv = bias[gc];
            #pragma unroll
            for (int mi = 0; mi < 8; ++mi) {
                int gr0 = mbase + wm * 128 + mi * 16 + qd * 4;
                int b = gr0 >> 12, tok = gr0 & 4095;
                us4 pk;
                #pragma unroll
                for (int r = 0; r < 4; ++r) pk[r] = f2bf(acc[mi][ni][r] + bv);
                *(us4*)(C + (((size_t)b * 16 + h) * 64 + dh) * 4096 + tok) = pk;
            }
        }
    }
}

__global__ __launch_bounds__(512, 2) void gemm256_out(
    const unsigned short* __restrict__ A, const unsigned short* __restrict__ W,
    const float* __restrict__ bias, float* __restrict__ out)
{
    GEMM256_CORE(A, W)
    #pragma unroll
    for (int ni = 0; ni < 4; ++ni) {
        int gc = nbase + wn * 64 + ni * 16 + lrow;
        float bv = bias[gc];
        #pragma unroll
        for (int mi = 0; mi < 8; ++mi) {
            int gr0 = mbase + wm * 128 + mi * 16 + qd * 4;
            #pragma unroll
            for (int r = 0; r < 4; ++r)
                out[(size_t)(gr0 + r) * DM + gc] = acc[mi][ni][r] + bv;
        }
    }
}

// ---------------------------------------------------------------------------
// Attention v3 (R5): 8 waves x 16 q-rows (512 thr). Same per-head direct
// global fragment loads, same wave-private P rows (NO barriers). Halved
// per-wave serial chain + 32 waves/CU resident (LDS caps 4 blocks/CU;
// 4 x 8 waves = 100% of cap vs 50% before) to hide the load->MFMA->softmax
// latency chain. T5 setprio around MFMA clusters (m191 regime: independent
// waves at different phases).
// ---------------------------------------------------------------------------
__global__ __launch_bounds__(512) void attn_v3(
    const unsigned short* __restrict__ qh, const unsigned short* __restrict__ kh,
    const unsigned short* __restrict__ vt, unsigned short* __restrict__ aout)
{
    const int gid = blockIdx.x;
    const int h  = gid & 15;
    const int wi = (gid >> 4) & 31;
    const int b  = gid >> 9;
    const int bh = b * 16 + h;

    const unsigned short* Qp = qh + ((size_t)bh * 4096 + wi * 128) * 64;
    const unsigned short* Kp = kh + ((size_t)bh * 4096 + wi * 128) * 64;
    const unsigned short* Vp = vt + (size_t)bh * 64 * 4096 + wi * 128;

    const int tid = threadIdx.x, lane = tid & 63, wv = tid >> 6;  // wv 0..7
    const int lrow = lane & 15, qd = lane >> 4, kof = qd * 8;

    __shared__ unsigned short Ps[128 * 136];   // 34.8 KB

    // ---- S = Q K^T (16 q-rows per wave) ----
    f32x4 acc[8] = {};
    #pragma unroll
    for (int ki = 0; ki < 2; ++ki) {
        bf16x8 a0 = *(const bf16x8*)(Qp + (wv * 16 + lrow) * 64 + ki * 32 + kof);
        __builtin_amdgcn_s_setprio(1);
        #pragma unroll
        for (int ni = 0; ni < 8; ++ni) {
            bf16x8 bb = *(const bf16x8*)(Kp + (ni * 16 + lrow) * 64 + ki * 32 + kof);
            acc[ni] = __builtin_amdgcn_mfma_f32_16x16x32_bf16(a0, bb, acc[ni], 0, 0, 0);
        }
        __builtin_amdgcn_s_setprio(0);
    }

    // ---- softmax over the 128 cols (cols live across the 16-lane groups) ----
    const float scale = 0.125f;
    #pragma unroll
    for (int r = 0; r < 4; ++r) {
        float sc[8];
        float mx = -3.4e38f;
        #pragma unroll
        for (int ni = 0; ni < 8; ++ni) { sc[ni] = acc[ni][r] * scale; mx = fmaxf(mx, sc[ni]); }
        mx = fmaxf(mx, __shfl_xor(mx, 1));
        mx = fmaxf(mx, __shfl_xor(mx, 2));
        mx = fmaxf(mx, __shfl_xor(mx, 4));
        mx = fmaxf(mx, __shfl_xor(mx, 8));
        float sum = 0.f;
        #pragma unroll
        for (int ni = 0; ni < 8; ++ni) { sc[ni] = __expf(sc[ni] - mx); sum += sc[ni]; }
        sum += __shfl_xor(sum, 1);
        sum += __shfl_xor(sum, 2);
        sum += __shfl_xor(sum, 4);
        sum += __shfl_xor(sum, 8);
        float inv = 1.0f / sum;
        #pragma unroll
        for (int ni = 0; ni < 8; ++ni) acc[ni][r] = sc[ni] * inv;
    }

    // ---- P to LDS (wave-private rows; no barrier needed) ----
    #pragma unroll
    for (int ni = 0; ni < 8; ++ni)
        #pragma unroll
        for (int r = 0; r < 4; ++r)
            Ps[(wv * 16 + qd * 4 + r) * 136 + ni * 16 + lrow] = f2bf(acc[ni][r]);

    // ---- O = P V (V fragments direct from global transposed layout) ----
    f32x4 o[4] = {};
    #pragma unroll
    for (int kj = 0; kj < 4; ++kj) {
        bf16x8 a0 = *(const bf16x8*)(Ps + (wv * 16 + lrow) * 136 + kj * 32 + kof);
        __builtin_amdgcn_s_setprio(1);
        #pragma unroll
        for (int nd = 0; nd < 4; ++nd) {
            bf16x8 bb = *(const bf16x8*)(Vp + (size_t)(nd * 16 + lrow) * 4096 + kj * 32 + kof);
            o[nd] = __builtin_amdgcn_mfma_f32_16x16x32_bf16(a0, bb, o[nd], 0, 0, 0);
        }
        __builtin_amdgcn_s_setprio(0);
    }

    // ---- write row-major [M][1024] bf16 for the out-projection GEMM ----
    #pragma unroll
    for (int nd = 0; nd < 4; ++nd)
        #pragma unroll
        for (int r = 0; r < 4; ++r) {
            int R = wv * 16 + qd * 4 + r;
            int c = h * 64 + nd * 16 + lrow;
            aout[(size_t)(b * 4096 + wi * 128 + R) * DM + c] = f2bf(o[nd][r]);
        }
}

// ===========================================================================
// Round-1 fallback pipeline (used only if ws_size is too small for the bf16
// pre-convert layout). Verified correct in Round 1.
// ===========================================================================
__global__ __launch_bounds__(256) void gemm_qkv_v1(
    const float* __restrict__ qin, const float* __restrict__ kin,
    const float* __restrict__ vin, const float* __restrict__ ipw,
    const float* __restrict__ ipb, unsigned short* __restrict__ qkv)
{
    __shared__ unsigned short As[128 * 40];
    __shared__ unsigned short Ws[128 * 40];
    const int z = blockIdx.z;
    const float* A  = (z == 0) ? qin : ((z == 1) ? kin : vin);
    const float* Wp = ipw + (size_t)z * DM * DM;
    const float* bp = ipb + z * DM;
    unsigned short* Cp = qkv + (size_t)z * M_TOK * DM;
    const int mbase = blockIdx.y * 128, nbase = blockIdx.x * 128;
    const int tid = threadIdx.x, lane = tid & 63, wv = tid >> 6;
    const int wrow = (wv >> 1) * 64, wcol = (wv & 1) * 64;
    const int lrow = lane & 15, kof = (lane >> 4) * 8;
    const int srow = tid >> 3, sc4 = tid & 7;
    f32x4 acc[4][4] = {};
    for (int ks = 0; ks < 32; ++ks) {
        const int k0 = ks * 32;
        __syncthreads();
        #pragma unroll
        for (int it = 0; it < 4; ++it) {
            int row = it * 32 + srow;
            float4 av = *(const float4*)(A  + (size_t)(mbase + row) * DM + k0 + sc4 * 4);
            float4 wf = *(const float4*)(Wp + (size_t)(nbase + row) * DM + k0 + sc4 * 4);
            us4 ap, wp4;
            ap[0] = f2bf(av.x); ap[1] = f2bf(av.y); ap[2] = f2bf(av.z); ap[3] = f2bf(av.w);
            wp4[0] = f2bf(wf.x); wp4[1] = f2bf(wf.y); wp4[2] = f2bf(wf.z); wp4[3] = f2bf(wf.w);
            *(us4*)(As + row * 40 + sc4 * 4) = ap;
            *(us4*)(Ws + row * 40 + sc4 * 4) = wp4;
        }
        __syncthreads();
        bf16x8 af[4], bfr[4];
        #pragma unroll
        for (int i = 0; i < 4; ++i) af[i]  = *(const bf16x8*)(As + (wrow + i * 16 + lrow) * 40 + kof);
        #pragma unroll
        for (int i = 0; i < 4; ++i) bfr[i] = *(const bf16x8*)(Ws + (wcol + i * 16 + lrow) * 40 + kof);
        #pragma unroll
        for (int i = 0; i < 4; ++i)
            #pragma unroll
            for (int j = 0; j < 4; ++j)
                acc[i][j] = __builtin_amdgcn_mfma_f32_16x16x32_bf16(af[i], bfr[j], acc[i][j], 0, 0, 0);
    }
    #pragma unroll
    for (int j = 0; j < 4; ++j) {
        int gc = nbase + wcol + j * 16 + lrow;
        float bv = bp[gc];
        #pragma unroll
        for (int i = 0; i < 4; ++i) {
            int gr0 = mbase + wrow + i * 16 + (lane >> 4) * 4;
            #pragma unroll
            for (int r = 0; r < 4; ++r)
                Cp[(size_t)(gr0 + r) * DM + gc] = f2bf(acc[i][j][r] + bv);
        }
    }
}

__global__ __launch_bounds__(256) void gemm_out_v1(
    const unsigned short* __restrict__ x, const float* __restrict__ ow,
    const float* __restrict__ ob, float* __restrict__ out)
{
    __shared__ unsigned short As[128 * 40];
    __shared__ unsigned short Ws[128 * 40];
    const int mbase = blockIdx.y * 128, nbase = blockIdx.x * 128;
    const int tid = threadIdx.x, lane = tid & 63, wv = tid >> 6;
    const int wrow = (wv >> 1) * 64, wcol = (wv & 1) * 64;
    const int lrow = lane & 15, kof = (lane >> 4) * 8;
    const int srow = tid >> 3, sc4 = tid & 7;
    f32x4 acc[4][4] = {};
    for (int ks = 0; ks < 32; ++ks) {
        const int k0 = ks * 32;
        __syncthreads();
        #pragma unroll
        for (int it = 0; it < 4; ++it) {
            int row = it * 32 + srow;
            us4 av = *(const us4*)(x + (size_t)(mbase + row) * DM + k0 + sc4 * 4);
            float4 wf = *(const float4*)(ow + (size_t)(nbase + row) * DM + k0 + sc4 * 4);
            us4 wp4;
            wp4[0] = f2bf(wf.x); wp4[1] = f2bf(wf.y); wp4[2] = f2bf(wf.z); wp4[3] = f2bf(wf.w);
            *(us4*)(As + row * 40 + sc4 * 4) = av;
            *(us4*)(Ws + row * 40 + sc4 * 4) = wp4;
        }
        __syncthreads();
        bf16x8 af[4], bfr[4];
        #pragma unroll
        for (int i = 0; i < 4; ++i) af[i]  = *(const bf16x8*)(As + (wrow + i * 16 + lrow) * 40 + kof);
        #pragma unroll
        for (int i = 0; i < 4; ++i) bfr[i] = *(const bf16x8*)(Ws + (wcol + i * 16 + lrow) * 40 + kof);
        #pragma unroll
        for (int i = 0; i < 4; ++i)
            #pragma unroll
            for (int j = 0; j < 4; ++j)
                acc[i][j] = __builtin_amdgcn_mfma_f32_16x16x32_bf16(af[i], bfr[j], acc[i][j], 0, 0, 0);
    }
    #pragma unroll
    for (int j = 0; j < 4; ++j) {
        int gc = nbase + wcol + j * 16 + lrow;
        float bv = ob[gc];
        #pragma unroll
        for (int i = 0; i < 4; ++i) {
            int gr0 = mbase + wrow + i * 16 + (lane >> 4) * 4;
            #pragma unroll
            for (int r = 0; r < 4; ++r)
                out[(size_t)(gr0 + r) * DM + gc] = acc[i][j][r] + bv;
        }
    }
}

__global__ __launch_bounds__(256) void attn_win_v1(
    const unsigned short* __restrict__ qkv, unsigned short* __restrict__ aout)
{
    const unsigned short* qp = qkv;
    const unsigned short* kp = qkv + (size_t)M_TOK * DM;
    const unsigned short* vp = qkv + 2 * (size_t)M_TOK * DM;
    const int gid = blockIdx.x;
    const int h = gid & 15, wi = (gid >> 4) & 31, b = gid >> 9;
    const size_t rowbase = (size_t)b * 4096 + (size_t)wi * 128;
    const int tid = threadIdx.x, lane = tid & 63, wv = tid >> 6;
    const int lrow = lane & 15, kof = (lane >> 4) * 8;
    __shared__ unsigned short sm[27136];
    unsigned short* Qs = sm;
    unsigned short* Ks = sm + 9216;
    unsigned short* Vt = sm + 18432;
    unsigned short* Ps = sm;
    {
        const int seg = tid & 7;
        #pragma unroll
        for (int it = 0; it < 4; ++it) {
            int r = it * 32 + (tid >> 3);
            size_t g = (rowbase + r) * DM + h * 64 + seg * 8;
            *(int4*)(Qs + r * 72 + seg * 8) = *(const int4*)(qp + g);
            *(int4*)(Ks + r * 72 + seg * 8) = *(const int4*)(kp + g);
        }
        #pragma unroll
        for (int it = 0; it < 4; ++it) {
            int j = tid & 127;
            int sg = it * 2 + (tid >> 7);
            us8 vv = *(const us8*)(vp + (rowbase + j) * DM + h * 64 + sg * 8);
            #pragma unroll
            for (int d = 0; d < 8; ++d) Vt[(sg * 8 + d) * 136 + j] = vv[d];
        }
    }
    __syncthreads();
    f32x4 acc[2][8] = {};
    #pragma unroll
    for (int ki = 0; ki < 2; ++ki) {
        bf16x8 a0 = *(const bf16x8*)(Qs + (wv * 32 +  0 + lrow) * 72 + ki * 32 + kof);
        bf16x8 a1 = *(const bf16x8*)(Qs + (wv * 32 + 16 + lrow) * 72 + ki * 32 + kof);
        #pragma unroll
        for (int ni = 0; ni < 8; ++ni) {
            bf16x8 bb = *(const bf16x8*)(Ks + (ni * 16 + lrow) * 72 + ki * 32 + kof);
            acc[0][ni] = __builtin_amdgcn_mfma_f32_16x16x32_bf16(a0, bb, acc[0][ni], 0, 0, 0);
            acc[1][ni] = __builtin_amdgcn_mfma_f32_16x16x32_bf16(a1, bb, acc[1][ni], 0, 0, 0);
        }
    }
    const float scale = 0.125f;
    #pragma unroll
    for (int mi = 0; mi < 2; ++mi) {
        #pragma unroll
        for (int r = 0; r < 4; ++r) {
            float sc[8];
            float mx = -3.4e38f;
            #pragma unroll
            for (int ni = 0; ni < 8; ++ni) { sc[ni] = acc[mi][ni][r] * scale; mx = fmaxf(mx, sc[ni]); }
            mx = fmaxf(mx, __shfl_xor(mx, 1)); mx = fmaxf(mx, __shfl_xor(mx, 2));
            mx = fmaxf(mx, __shfl_xor(mx, 4)); mx = fmaxf(mx, __shfl_xor(mx, 8));
            float sum = 0.f;
            #pragma unroll
            for (int ni = 0; ni < 8; ++ni) { sc[ni] = __expf(sc[ni] - mx); sum += sc[ni]; }
            sum += __shfl_xor(sum, 1); sum += __shfl_xor(sum, 2);
            sum += __shfl_xor(sum, 4); sum += __shfl_xor(sum, 8);
            float inv = 1.0f / sum;
            #pragma unroll
            for (int ni = 0; ni < 8; ++ni) acc[mi][ni][r] = sc[ni] * inv;
        }
    }
    __syncthreads();
    #pragma unroll
    for (int mi = 0; mi < 2; ++mi)
        #pragma unroll
        for (int ni = 0; ni < 8; ++ni)
            #pragma unroll
            for (int r = 0; r < 4; ++r)
                Ps[(wv * 32 + mi * 16 + (lane >> 4) * 4 + r) * 136 + ni * 16 + lrow] =
                    f2bf(acc[mi][ni][r]);
    __syncthreads();
    f32x4 o[2][4] = {};
    #pragma unroll
    for (int kj = 0; kj < 4; ++kj) {
        bf16x8 a0 = *(const bf16x8*)(Ps + (wv * 32 +  0 + lrow) * 136 + kj * 32 + kof);
        bf16x8 a1 = *(const bf16x8*)(Ps + (wv * 32 + 16 + lrow) * 136 + kj * 32 + kof);
        #pragma unroll
        for (int nd = 0; nd < 4; ++nd) {
            bf16x8 bb = *(const bf16x8*)(Vt + (nd * 16 + lrow) * 136 + kj * 32 + kof);
            o[0][nd] = __builtin_amdgcn_mfma_f32_16x16x32_bf16(a0, bb, o[0][nd], 0, 0, 0);
            o[1][nd] = __builtin_amdgcn_mfma_f32_16x16x32_bf16(a1, bb, o[1][nd], 0, 0, 0);
        }
    }
    #pragma unroll
    for (int mi = 0; mi < 2; ++mi)
        #pragma unroll
        for (int nd = 0; nd < 4; ++nd)
            #pragma unroll
            for (int r = 0; r < 4; ++r) {
                int R = wv * 32 + mi * 16 + (lane >> 4) * 4 + r;
                int c = h * 64 + nd * 16 + lrow;
                aout[(rowbase + R) * DM + c] = f2bf(o[mi][nd][r]);
            }
}

// ---------------------------------------------------------------------------
extern "C" void kernel_launch(void* const* d_in, const int* in_sizes, int n_in,
                              void* d_out, int out_size, void* d_ws, size_t ws_size,
                              hipStream_t stream) {
    const float* q   = (const float*)d_in[0];
    const float* k   = (const float*)d_in[1];
    const float* v   = (const float*)d_in[2];
    const float* ipw = (const float*)d_in[3];
    const float* ipb = (const float*)d_in[4];
    const float* ow  = (const float*)d_in[5];
    const float* ob  = (const float*)d_in[6];
    float* out = (float*)d_out;

    const size_t MD = (size_t)M_TOK * DM;          // 16,777,216 elems
    const size_t WW = (size_t)DM * DM;             // 1,048,576 elems
    const size_t need = (4 * MD + 3 * WW) * 2;     // 140,509,184 B

    if (ws_size >= need) {
        unsigned short* X   = (unsigned short*)d_ws;       // one fp32->bf16 slot
        unsigned short* qh  = X + MD;
        unsigned short* kh  = X + 2 * MD;
        unsigned short* vtb = X + 3 * MD;
        unsigned short* Wb  = X + 4 * MD;                  // 3 weight mats bf16
        unsigned short* aout = X;                          // alias (X dead after gemms)
        unsigned short* OwB  = Wb;                         // alias (Wb dead after gemms)

        conv_f2b<<<1536, 256, 0, stream>>>(ipw, Wb, (int)(3 * WW / 8));
        conv_f2b<<<8192, 256, 0, stream>>>(q, X, (int)(MD / 8));
        gemm256_qkv<<<dim3(4, 64), 512, 0, stream>>>(X, Wb, ipb, qh, 0);
        conv_f2b<<<8192, 256, 0, stream>>>(k, X, (int)(MD / 8));
        gemm256_qkv<<<dim3(4, 64), 512, 0, stream>>>(X, Wb + WW, ipb + DM, kh, 1);
        conv_f2b<<<8192, 256, 0, stream>>>(v, X, (int)(MD / 8));
        gemm256_qkv<<<dim3(4, 64), 512, 0, stream>>>(X, Wb + 2 * WW, ipb + 2 * DM, vtb, 2);
        conv_f2b<<<512, 256, 0, stream>>>(ow, OwB, (int)(WW / 8));
        attn_v3<<<2048, 512, 0, stream>>>(qh, kh, vtb, aout);
        gemm256_out<<<dim3(4, 64), 512, 0, stream>>>(aout, OwB, ob, out);
    } else {
        // Round-1 fallback (needs 100.7 MB, aliases aout onto qkv if tight)
        unsigned short* qkv = (unsigned short*)d_ws;
        const size_t qkv_elems = 3 * MD;
        const size_t need_full = (qkv_elems + MD) * 2;
        unsigned short* aout = (ws_size >= need_full) ? qkv + qkv_elems : qkv;
        gemm_qkv_v1<<<dim3(8, 128, 3), 256, 0, stream>>>(q, k, v, ipw, ipb, qkv);
        attn_win_v1<<<2048, 256, 0, stream>>>(qkv, aout);
        gemm_out_v1<<<dim3(8, 128), 256, 0, stream>>>(aout, ow, ob, out);
    }
}

// Round 7
// 459.247 us; speedup vs baseline: 1.0362x; 1.0362x over previous
//
#include <hip/hip_runtime.h>

// LocalAttention: B=4, L=4096, D=1024, H=16, hd=64, WINDOW=128, nW=32
#define M_TOK 16384
#define DM    1024

typedef __bf16 bf16x8 __attribute__((ext_vector_type(8)));
typedef float  f32x4  __attribute__((ext_vector_type(4)));
typedef unsigned short us8 __attribute__((ext_vector_type(8)));
typedef unsigned short us4 __attribute__((ext_vector_type(4)));

__device__ __forceinline__ unsigned short f2bf(float f) {
    unsigned u = __float_as_uint(f);
    u += 0x7FFFu + ((u >> 16) & 1u);   // RNE
    return (unsigned short)(u >> 16);
}

__device__ __forceinline__ void gl2lds16(const unsigned short* g, unsigned short* l) {
    __builtin_amdgcn_global_load_lds(
        (const __attribute__((address_space(1))) unsigned int*)g,
        (__attribute__((address_space(3))) unsigned int*)l, 16, 0, 0);
}

// ---------------------------------------------------------------------------
// fp32 -> bf16 stream convert, 8 elems/thread
// ---------------------------------------------------------------------------
__global__ __launch_bounds__(256) void conv_f2b(
    const float* __restrict__ src, unsigned short* __restrict__ dst, int n8)
{
    int i = blockIdx.x * blockDim.x + threadIdx.x;
    int stride = gridDim.x * blockDim.x;
    for (; i < n8; i += stride) {
        const float4* s = (const float4*)(src + (size_t)i * 8);
        float4 a = s[0], b = s[1];
        us8 o;
        o[0] = f2bf(a.x); o[1] = f2bf(a.y); o[2] = f2bf(a.z); o[3] = f2bf(a.w);
        o[4] = f2bf(b.x); o[5] = f2bf(b.y); o[6] = f2bf(b.z); o[7] = f2bf(b.w);
        *(us8*)(dst + (size_t)i * 8) = o;
    }
}

// ---------------------------------------------------------------------------
// R4 (kept verbatim, verified): 256x256-tile bf16 NT-GEMM, 512 thr, K split
// into 32 k-halves. LDS = 4-slot ring per matrix (128KB). Stage-issue INSIDE
// the compute phase; counted vmcnt(4); never vmcnt(0) until tail.
// ---------------------------------------------------------------------------
#define STAGE_HALF(x_)                                                       \
    {                                                                        \
        const int s_ = ((x_) & 3) * 8192;                                    \
        _Pragma("unroll")                                                    \
        for (int j = 0; j < 2; ++j) {                                        \
            int p = tid + j * 512;                                           \
            int r = p >> 2, cp = p & 3;                                      \
            int cl = cp ^ ((r >> 1) & 3);                                    \
            gl2lds16(Ab + (size_t)r * DM + (x_) * 32 + cl * 8,               \
                     LA + s_ + p * 8);                                       \
            gl2lds16(Bb + (size_t)r * DM + (x_) * 32 + cl * 8,               \
                     LB + s_ + p * 8);                                       \
        }                                                                    \
    }

#define GEMM256_CORE(A_, B_)                                                 \
    __shared__ unsigned short smem[65536]; /* 128 KB */                      \
    const int tid = threadIdx.x, lane = tid & 63, wv = tid >> 6;             \
    const int wm = wv >> 2, wn = wv & 3;                                     \
    const int lrow = lane & 15, qd = lane >> 4;                              \
    const int orig = blockIdx.y * 4 + blockIdx.x;  /* grid (4,64) = 256 */   \
    const int swz  = (orig & 7) * 32 + (orig >> 3);                          \
    const int mbase = (swz >> 2) * 256, nbase = (swz & 3) * 256;             \
    const unsigned short* Ab = (A_) + (size_t)mbase * DM;                    \
    const unsigned short* Bb = (B_) + (size_t)nbase * DM;                    \
    unsigned short* LA = smem;                                               \
    unsigned short* LB = smem + 32768;                                       \
    const int fsw  = (qd ^ ((lrow >> 1) & 3)) * 8;                           \
    const int aoff = (wm * 128 + lrow) * 32 + fsw;                           \
    const int boff = (wn * 64 + lrow) * 32 + fsw;                            \
    f32x4 acc[8][4] = {};                                                    \
    STAGE_HALF(0)                                                            \
    STAGE_HALF(1)                                                            \
    asm volatile("s_waitcnt vmcnt(4)" ::: "memory");                         \
    __builtin_amdgcn_s_barrier();                                            \
    __builtin_amdgcn_sched_barrier(0);                                       \
    _Pragma("unroll 4")                                                      \
    for (int kh = 0; kh < 32; ++kh) {                                        \
        if (kh < 30) STAGE_HALF(kh + 2)                                      \
        const int sb = (kh & 3) * 8192;                                      \
        bf16x8 af[8], bb[4];                                                 \
        _Pragma("unroll")                                                    \
        for (int mi = 0; mi < 8; ++mi)                                       \
            af[mi] = *(const bf16x8*)(LA + sb + aoff + mi * 512);            \
        _Pragma("unroll")                                                    \
        for (int ni = 0; ni < 4; ++ni)                                       \
            bb[ni] = *(const bf16x8*)(LB + sb + boff + ni * 512);            \
        __builtin_amdgcn_s_setprio(1);                                       \
        _Pragma("unroll")                                                    \
        for (int mi = 0; mi < 8; ++mi)                                       \
            _Pragma("unroll")                                                \
            for (int ni = 0; ni < 4; ++ni)                                   \
                acc[mi][ni] = __builtin_amdgcn_mfma_f32_16x16x32_bf16(       \
                    af[mi], bb[ni], acc[mi][ni], 0, 0, 0);                   \
        __builtin_amdgcn_s_setprio(0);                                       \
        if (kh < 30) { asm volatile("s_waitcnt vmcnt(4)" ::: "memory"); }    \
        else         { asm volatile("s_waitcnt vmcnt(0)" ::: "memory"); }    \
        __builtin_amdgcn_s_barrier();                                        \
        __builtin_amdgcn_sched_barrier(0);                                   \
    }

// GEMM producing attention-friendly layouts:
// z=0/1: C[((b*16+h)*4096 + tok)*64 + dh]   (per-head row-major Q/K)
// z=2  : C[((b*16+h)*64 + dh)*4096 + tok]   (per-head TRANSPOSED V)
__global__ __launch_bounds__(512, 2) void gemm256_qkv(
    const unsigned short* __restrict__ A, const unsigned short* __restrict__ W,
    const float* __restrict__ bias, unsigned short* __restrict__ C, int z)
{
    GEMM256_CORE(A, W)
    if (z <= 1) {
        #pragma unroll
        for (int ni = 0; ni < 4; ++ni) {
            int gc = nbase + wn * 64 + ni * 16 + lrow;
            int h = gc >> 6, dh = gc & 63;
            float bv = bias[gc];
            #pragma unroll
            for (int mi = 0; mi < 8; ++mi) {
                int gr0 = mbase + wm * 128 + mi * 16 + qd * 4;
                int b = gr0 >> 12;
                #pragma unroll
                for (int r = 0; r < 4; ++r) {
                    int tok = (gr0 + r) & 4095;
                    C[(((size_t)b * 16 + h) * 4096 + tok) * 64 + dh] =
                        f2bf(acc[mi][ni][r] + bv);
                }
            }
        }
    } else {
        #pragma unroll
        for (int ni = 0; ni < 4; ++ni) {
            int gc = nbase + wn * 64 + ni * 16 + lrow;
            int h = gc >> 6, dh = gc & 63;
            float bv = bias[gc];
            #pragma unroll
            for (int mi = 0; mi < 8; ++mi) {
                int gr0 = mbase + wm * 128 + mi * 16 + qd * 4;
                int b = gr0 >> 12, tok = gr0 & 4095;
                us4 pk;
                #pragma unroll
                for (int r = 0; r < 4; ++r) pk[r] = f2bf(acc[mi][ni][r] + bv);
                *(us4*)(C + (((size_t)b * 16 + h) * 64 + dh) * 4096 + tok) = pk;
            }
        }
    }
}

__global__ __launch_bounds__(512, 2) void gemm256_out(
    const unsigned short* __restrict__ A, const unsigned short* __restrict__ W,
    const float* __restrict__ bias, float* __restrict__ out)
{
    GEMM256_CORE(A, W)
    #pragma unroll
    for (int ni = 0; ni < 4; ++ni) {
        int gc = nbase + wn * 64 + ni * 16 + lrow;
        float bv = bias[gc];
        #pragma unroll
        for (int mi = 0; mi < 8; ++mi) {
            int gr0 = mbase + wm * 128 + mi * 16 + qd * 4;
            #pragma unroll
            for (int r = 0; r < 4; ++r)
                out[(size_t)(gr0 + r) * DM + gc] = acc[mi][ni][r] + bv;
        }
    }
}

// ---------------------------------------------------------------------------
// Attention v4 (R6): v2 shape (4 waves x 32 q-rows, 256 thr) + load dedup.
//  - K staged ONCE to LDS (reg-staged, stride 68 = 136B, overlaid on Ps rows
//    64+); QK^T B-frags become LDS reads. Removes the 4x duplicated K global
//    reads that v3 showed to be the latency driver.
//  - V frags for kj=0,1 prefetched to regs before softmax (T14): HBM latency
//    hides under the ~1400-cyc softmax chain. kj=2,3 stay direct.
//  - Q frags hoisted before the barrier.
//  - barrier #1: K stage -> QK^T reads; barrier #2: QK^T -> P writes (waves
//    2,3's P rows clobber the K overlay).
// ---------------------------------------------------------------------------
__global__ __launch_bounds__(256, 4) void attn_v4(
    const unsigned short* __restrict__ qh, const unsigned short* __restrict__ kh,
    const unsigned short* __restrict__ vt, unsigned short* __restrict__ aout)
{
    const int gid = blockIdx.x;
    const int h  = gid & 15;
    const int wi = (gid >> 4) & 31;
    const int b  = gid >> 9;
    const int bh = b * 16 + h;

    const unsigned short* Qp = qh + ((size_t)bh * 4096 + wi * 128) * 64;
    const unsigned short* Kp = kh + ((size_t)bh * 4096 + wi * 128) * 64;
    const unsigned short* Vp = vt + (size_t)bh * 64 * 4096 + wi * 128;

    const int tid = threadIdx.x, lane = tid & 63, wv = tid >> 6;
    const int lrow = lane & 15, qd = lane >> 4, kof = qd * 8;

    __shared__ unsigned short Ps[128 * 136];   // 34.8 KB
    unsigned short* Ks = Ps + 64 * 136;        // K overlay: 128 rows x stride 68
                                               // (uses 8700 of the 8704 elems)

    // ---- stage K[128][64] -> LDS (reg-staged; 2 us8 loads + 2 writes/thr) ----
    #pragma unroll
    for (int j = 0; j < 2; ++j) {
        int s = tid + j * 256;                 // 512 slots of 16 elems
        int r = s >> 2, c = s & 3;             // row 0..127, 16-elem col 0..3
        us8 v0 = *(const us8*)(Kp + r * 64 + c * 16);
        us8 v1 = *(const us8*)(Kp + r * 64 + c * 16 + 8);
        *(us8*)(Ks + r * 68 + c * 16)     = v0;
        *(us8*)(Ks + r * 68 + c * 16 + 8) = v1;
    }

    // ---- V prefetch kj=0,1 (independent of K/softmax; 32 VGPR) ----
    bf16x8 vpre[2][4];
    #pragma unroll
    for (int kj = 0; kj < 2; ++kj)
        #pragma unroll
        for (int nd = 0; nd < 4; ++nd)
            vpre[kj][nd] = *(const bf16x8*)(Vp + (size_t)(nd * 16 + lrow) * 4096 + kj * 32 + kof);

    // ---- Q frags hoisted ----
    bf16x8 qf[2][2];
    #pragma unroll
    for (int ki = 0; ki < 2; ++ki) {
        qf[ki][0] = *(const bf16x8*)(Qp + (wv * 32 +  0 + lrow) * 64 + ki * 32 + kof);
        qf[ki][1] = *(const bf16x8*)(Qp + (wv * 32 + 16 + lrow) * 64 + ki * 32 + kof);
    }

    __syncthreads();   // K staged & visible

    // ---- S = Q K^T (K from LDS) ----
    f32x4 acc[2][8] = {};
    #pragma unroll
    for (int ki = 0; ki < 2; ++ki) {
        #pragma unroll
        for (int ni = 0; ni < 8; ++ni) {
            bf16x8 bb = *(const bf16x8*)(Ks + (ni * 16 + lrow) * 68 + ki * 32 + kof);
            acc[0][ni] = __builtin_amdgcn_mfma_f32_16x16x32_bf16(qf[ki][0], bb, acc[0][ni], 0, 0, 0);
            acc[1][ni] = __builtin_amdgcn_mfma_f32_16x16x32_bf16(qf[ki][1], bb, acc[1][ni], 0, 0, 0);
        }
    }

    __syncthreads();   // all waves done reading K before P rows 64+ overwrite it

    // ---- softmax over the 128 cols (cols live across the 16-lane groups) ----
    const float scale = 0.125f;
    #pragma unroll
    for (int mi = 0; mi < 2; ++mi) {
        #pragma unroll
        for (int r = 0; r < 4; ++r) {
            float sc[8];
            float mx = -3.4e38f;
            #pragma unroll
            for (int ni = 0; ni < 8; ++ni) { sc[ni] = acc[mi][ni][r] * scale; mx = fmaxf(mx, sc[ni]); }
            mx = fmaxf(mx, __shfl_xor(mx, 1));
            mx = fmaxf(mx, __shfl_xor(mx, 2));
            mx = fmaxf(mx, __shfl_xor(mx, 4));
            mx = fmaxf(mx, __shfl_xor(mx, 8));
            float sum = 0.f;
            #pragma unroll
            for (int ni = 0; ni < 8; ++ni) { sc[ni] = __expf(sc[ni] - mx); sum += sc[ni]; }
            sum += __shfl_xor(sum, 1);
            sum += __shfl_xor(sum, 2);
            sum += __shfl_xor(sum, 4);
            sum += __shfl_xor(sum, 8);
            float inv = 1.0f / sum;
            #pragma unroll
            for (int ni = 0; ni < 8; ++ni) acc[mi][ni][r] = sc[ni] * inv;
        }
    }

    // ---- P to LDS (wave-private rows; no barrier needed) ----
    #pragma unroll
    for (int mi = 0; mi < 2; ++mi)
        #pragma unroll
        for (int ni = 0; ni < 8; ++ni)
            #pragma unroll
            for (int r = 0; r < 4; ++r)
                Ps[(wv * 32 + mi * 16 + qd * 4 + r) * 136 + ni * 16 + lrow] =
                    f2bf(acc[mi][ni][r]);

    // ---- O = P V (kj 0,1 from prefetched regs; kj 2,3 direct) ----
    f32x4 o[2][4] = {};
    #pragma unroll
    for (int kj = 0; kj < 4; ++kj) {
        bf16x8 a0 = *(const bf16x8*)(Ps + (wv * 32 +  0 + lrow) * 136 + kj * 32 + kof);
        bf16x8 a1 = *(const bf16x8*)(Ps + (wv * 32 + 16 + lrow) * 136 + kj * 32 + kof);
        #pragma unroll
        for (int nd = 0; nd < 4; ++nd) {
            bf16x8 bb = (kj < 2) ? vpre[kj][nd]
                : *(const bf16x8*)(Vp + (size_t)(nd * 16 + lrow) * 4096 + kj * 32 + kof);
            o[0][nd] = __builtin_amdgcn_mfma_f32_16x16x32_bf16(a0, bb, o[0][nd], 0, 0, 0);
            o[1][nd] = __builtin_amdgcn_mfma_f32_16x16x32_bf16(a1, bb, o[1][nd], 0, 0, 0);
        }
    }

    // ---- write row-major [M][1024] bf16 for the out-projection GEMM ----
    #pragma unroll
    for (int mi = 0; mi < 2; ++mi)
        #pragma unroll
        for (int nd = 0; nd < 4; ++nd)
            #pragma unroll
            for (int r = 0; r < 4; ++r) {
                int R = wv * 32 + mi * 16 + qd * 4 + r;
                int c = h * 64 + nd * 16 + lrow;
                aout[(size_t)(b * 4096 + wi * 128 + R) * DM + c] = f2bf(o[mi][nd][r]);
            }
}

// ===========================================================================
// Round-1 fallback pipeline (used only if ws_size is too small for the bf16
// pre-convert layout). Verified correct in Round 1.
// ===========================================================================
__global__ __launch_bounds__(256) void gemm_qkv_v1(
    const float* __restrict__ qin, const float* __restrict__ kin,
    const float* __restrict__ vin, const float* __restrict__ ipw,
    const float* __restrict__ ipb, unsigned short* __restrict__ qkv)
{
    __shared__ unsigned short As[128 * 40];
    __shared__ unsigned short Ws[128 * 40];
    const int z = blockIdx.z;
    const float* A  = (z == 0) ? qin : ((z == 1) ? kin : vin);
    const float* Wp = ipw + (size_t)z * DM * DM;
    const float* bp = ipb + z * DM;
    unsigned short* Cp = qkv + (size_t)z * M_TOK * DM;
    const int mbase = blockIdx.y * 128, nbase = blockIdx.x * 128;
    const int tid = threadIdx.x, lane = tid & 63, wv = tid >> 6;
    const int wrow = (wv >> 1) * 64, wcol = (wv & 1) * 64;
    const int lrow = lane & 15, kof = (lane >> 4) * 8;
    const int srow = tid >> 3, sc4 = tid & 7;
    f32x4 acc[4][4] = {};
    for (int ks = 0; ks < 32; ++ks) {
        const int k0 = ks * 32;
        __syncthreads();
        #pragma unroll
        for (int it = 0; it < 4; ++it) {
            int row = it * 32 + srow;
            float4 av = *(const float4*)(A  + (size_t)(mbase + row) * DM + k0 + sc4 * 4);
            float4 wf = *(const float4*)(Wp + (size_t)(nbase + row) * DM + k0 + sc4 * 4);
            us4 ap, wp4;
            ap[0] = f2bf(av.x); ap[1] = f2bf(av.y); ap[2] = f2bf(av.z); ap[3] = f2bf(av.w);
            wp4[0] = f2bf(wf.x); wp4[1] = f2bf(wf.y); wp4[2] = f2bf(wf.z); wp4[3] = f2bf(wf.w);
            *(us4*)(As + row * 40 + sc4 * 4) = ap;
            *(us4*)(Ws + row * 40 + sc4 * 4) = wp4;
        }
        __syncthreads();
        bf16x8 af[4], bfr[4];
        #pragma unroll
        for (int i = 0; i < 4; ++i) af[i]  = *(const bf16x8*)(As + (wrow + i * 16 + lrow) * 40 + kof);
        #pragma unroll
        for (int i = 0; i < 4; ++i) bfr[i] = *(const bf16x8*)(Ws + (wcol + i * 16 + lrow) * 40 + kof);
        #pragma unroll
        for (int i = 0; i < 4; ++i)
            #pragma unroll
            for (int j = 0; j < 4; ++j)
                acc[i][j] = __builtin_amdgcn_mfma_f32_16x16x32_bf16(af[i], bfr[j], acc[i][j], 0, 0, 0);
    }
    #pragma unroll
    for (int j = 0; j < 4; ++j) {
        int gc = nbase + wcol + j * 16 + lrow;
        float bv = bp[gc];
        #pragma unroll
        for (int i = 0; i < 4; ++i) {
            int gr0 = mbase + wrow + i * 16 + (lane >> 4) * 4;
            #pragma unroll
            for (int r = 0; r < 4; ++r)
                Cp[(size_t)(gr0 + r) * DM + gc] = f2bf(acc[i][j][r] + bv);
        }
    }
}

__global__ __launch_bounds__(256) void gemm_out_v1(
    const unsigned short* __restrict__ x, const float* __restrict__ ow,
    const float* __restrict__ ob, float* __restrict__ out)
{
    __shared__ unsigned short As[128 * 40];
    __shared__ unsigned short Ws[128 * 40];
    const int mbase = blockIdx.y * 128, nbase = blockIdx.x * 128;
    const int tid = threadIdx.x, lane = tid & 63, wv = tid >> 6;
    const int wrow = (wv >> 1) * 64, wcol = (wv & 1) * 64;
    const int lrow = lane & 15, kof = (lane >> 4) * 8;
    const int srow = tid >> 3, sc4 = tid & 7;
    f32x4 acc[4][4] = {};
    for (int ks = 0; ks < 32; ++ks) {
        const int k0 = ks * 32;
        __syncthreads();
        #pragma unroll
        for (int it = 0; it < 4; ++it) {
            int row = it * 32 + srow;
            us4 av = *(const us4*)(x + (size_t)(mbase + row) * DM + k0 + sc4 * 4);
            float4 wf = *(const float4*)(ow + (size_t)(nbase + row) * DM + k0 + sc4 * 4);
            us4 wp4;
            wp4[0] = f2bf(wf.x); wp4[1] = f2bf(wf.y); wp4[2] = f2bf(wf.z); wp4[3] = f2bf(wf.w);
            *(us4*)(As + row * 40 + sc4 * 4) = av;
            *(us4*)(Ws + row * 40 + sc4 * 4) = wp4;
        }
        __syncthreads();
        bf16x8 af[4], bfr[4];
        #pragma unroll
        for (int i = 0; i < 4; ++i) af[i]  = *(const bf16x8*)(As + (wrow + i * 16 + lrow) * 40 + kof);
        #pragma unroll
        for (int i = 0; i < 4; ++i) bfr[i] = *(const bf16x8*)(Ws + (wcol + i * 16 + lrow) * 40 + kof);
        #pragma unroll
        for (int i = 0; i < 4; ++i)
            #pragma unroll
            for (int j = 0; j < 4; ++j)
                acc[i][j] = __builtin_amdgcn_mfma_f32_16x16x32_bf16(af[i], bfr[j], acc[i][j], 0, 0, 0);
    }
    #pragma unroll
    for (int j = 0; j < 4; ++j) {
        int gc = nbase + wcol + j * 16 + lrow;
        float bv = ob[gc];
        #pragma unroll
        for (int i = 0; i < 4; ++i) {
            int gr0 = mbase + wrow + i * 16 + (lane >> 4) * 4;
            #pragma unroll
            for (int r = 0; r < 4; ++r)
                out[(size_t)(gr0 + r) * DM + gc] = acc[i][j][r] + bv;
        }
    }
}

__global__ __launch_bounds__(256) void attn_win_v1(
    const unsigned short* __restrict__ qkv, unsigned short* __restrict__ aout)
{
    const unsigned short* qp = qkv;
    const unsigned short* kp = qkv + (size_t)M_TOK * DM;
    const unsigned short* vp = qkv + 2 * (size_t)M_TOK * DM;
    const int gid = blockIdx.x;
    const int h = gid & 15, wi = (gid >> 4) & 31, b = gid >> 9;
    const size_t rowbase = (size_t)b * 4096 + (size_t)wi * 128;
    const int tid = threadIdx.x, lane = tid & 63, wv = tid >> 6;
    const int lrow = lane & 15, kof = (lane >> 4) * 8;
    __shared__ unsigned short sm[27136];
    unsigned short* Qs = sm;
    unsigned short* Ks = sm + 9216;
    unsigned short* Vt = sm + 18432;
    unsigned short* Ps = sm;
    {
        const int seg = tid & 7;
        #pragma unroll
        for (int it = 0; it < 4; ++it) {
            int r = it * 32 + (tid >> 3);
            size_t g = (rowbase + r) * DM + h * 64 + seg * 8;
            *(int4*)(Qs + r * 72 + seg * 8) = *(const int4*)(qp + g);
            *(int4*)(Ks + r * 72 + seg * 8) = *(const int4*)(kp + g);
        }
        #pragma unroll
        for (int it = 0; it < 4; ++it) {
            int j = tid & 127;
            int sg = it * 2 + (tid >> 7);
            us8 vv = *(const us8*)(vp + (rowbase + j) * DM + h * 64 + sg * 8);
            #pragma unroll
            for (int d = 0; d < 8; ++d) Vt[(sg * 8 + d) * 136 + j] = vv[d];
        }
    }
    __syncthreads();
    f32x4 acc[2][8] = {};
    #pragma unroll
    for (int ki = 0; ki < 2; ++ki) {
        bf16x8 a0 = *(const bf16x8*)(Qs + (wv * 32 +  0 + lrow) * 72 + ki * 32 + kof);
        bf16x8 a1 = *(const bf16x8*)(Qs + (wv * 32 + 16 + lrow) * 72 + ki * 32 + kof);
        #pragma unroll
        for (int ni = 0; ni < 8; ++ni) {
            bf16x8 bb = *(const bf16x8*)(Ks + (ni * 16 + lrow) * 72 + ki * 32 + kof);
            acc[0][ni] = __builtin_amdgcn_mfma_f32_16x16x32_bf16(a0, bb, acc[0][ni], 0, 0, 0);
            acc[1][ni] = __builtin_amdgcn_mfma_f32_16x16x32_bf16(a1, bb, acc[1][ni], 0, 0, 0);
        }
    }
    const float scale = 0.125f;
    #pragma unroll
    for (int mi = 0; mi < 2; ++mi) {
        #pragma unroll
        for (int r = 0; r < 4; ++r) {
            float sc[8];
            float mx = -3.4e38f;
            #pragma unroll
            for (int ni = 0; ni < 8; ++ni) { sc[ni] = acc[mi][ni][r] * scale; mx = fmaxf(mx, sc[ni]); }
            mx = fmaxf(mx, __shfl_xor(mx, 1)); mx = fmaxf(mx, __shfl_xor(mx, 2));
            mx = fmaxf(mx, __shfl_xor(mx, 4)); mx = fmaxf(mx, __shfl_xor(mx, 8));
            float sum = 0.f;
            #pragma unroll
            for (int ni = 0; ni < 8; ++ni) { sc[ni] = __expf(sc[ni] - mx); sum += sc[ni]; }
            sum += __shfl_xor(sum, 1); sum += __shfl_xor(sum, 2);
            sum += __shfl_xor(sum, 4); sum += __shfl_xor(sum, 8);
            float inv = 1.0f / sum;
            #pragma unroll
            for (int ni = 0; ni < 8; ++ni) acc[mi][ni][r] = sc[ni] * inv;
        }
    }
    __syncthreads();
    #pragma unroll
    for (int mi = 0; mi < 2; ++mi)
        #pragma unroll
        for (int ni = 0; ni < 8; ++ni)
            #pragma unroll
            for (int r = 0; r < 4; ++r)
                Ps[(wv * 32 + mi * 16 + (lane >> 4) * 4 + r) * 136 + ni * 16 + lrow] =
                    f2bf(acc[mi][ni][r]);
    __syncthreads();
    f32x4 o[2][4] = {};
    #pragma unroll
    for (int kj = 0; kj < 4; ++kj) {
        bf16x8 a0 = *(const bf16x8*)(Ps + (wv * 32 +  0 + lrow) * 136 + kj * 32 + kof);
        bf16x8 a1 = *(const bf16x8*)(Ps + (wv * 32 + 16 + lrow) * 136 + kj * 32 + kof);
        #pragma unroll
        for (int nd = 0; nd < 4; ++nd) {
            bf16x8 bb = *(const bf16x8*)(Vt + (nd * 16 + lrow) * 136 + kj * 32 + kof);
            o[0][nd] = __builtin_amdgcn_mfma_f32_16x16x32_bf16(a0, bb, o[0][nd], 0, 0, 0);
            o[1][nd] = __builtin_amdgcn_mfma_f32_16x16x32_bf16(a1, bb, o[1][nd], 0, 0, 0);
        }
    }
    #pragma unroll
    for (int mi = 0; mi < 2; ++mi)
        #pragma unroll
        for (int nd = 0; nd < 4; ++nd)
            #pragma unroll
            for (int r = 0; r < 4; ++r) {
                int R = wv * 32 + mi * 16 + (lane >> 4) * 4 + r;
                int c = h * 64 + nd * 16 + lrow;
                aout[(rowbase + R) * DM + c] = f2bf(o[mi][nd][r]);
            }
}

// ---------------------------------------------------------------------------
extern "C" void kernel_launch(void* const* d_in, const int* in_sizes, int n_in,
                              void* d_out, int out_size, void* d_ws, size_t ws_size,
                              hipStream_t stream) {
    const float* q   = (const float*)d_in[0];
    const float* k   = (const float*)d_in[1];
    const float* v   = (const float*)d_in[2];
    const float* ipw = (const float*)d_in[3];
    const float* ipb = (const float*)d_in[4];
    const float* ow  = (const float*)d_in[5];
    const float* ob  = (const float*)d_in[6];
    float* out = (float*)d_out;

    const size_t MD = (size_t)M_TOK * DM;          // 16,777,216 elems
    const size_t WW = (size_t)DM * DM;             // 1,048,576 elems
    const size_t need = (4 * MD + 3 * WW) * 2;     // 140,509,184 B

    if (ws_size >= need) {
        unsigned short* X   = (unsigned short*)d_ws;       // one fp32->bf16 slot
        unsigned short* qh  = X + MD;
        unsigned short* kh  = X + 2 * MD;
        unsigned short* vtb = X + 3 * MD;
        unsigned short* Wb  = X + 4 * MD;                  // 3 weight mats bf16
        unsigned short* aout = X;                          // alias (X dead after gemms)
        unsigned short* OwB  = Wb;                         // alias (Wb dead after gemms)

        conv_f2b<<<1536, 256, 0, stream>>>(ipw, Wb, (int)(3 * WW / 8));
        conv_f2b<<<8192, 256, 0, stream>>>(q, X, (int)(MD / 8));
        gemm256_qkv<<<dim3(4, 64), 512, 0, stream>>>(X, Wb, ipb, qh, 0);
        conv_f2b<<<8192, 256, 0, stream>>>(k, X, (int)(MD / 8));
        gemm256_qkv<<<dim3(4, 64), 512, 0, stream>>>(X, Wb + WW, ipb + DM, kh, 1);
        conv_f2b<<<8192, 256, 0, stream>>>(v, X, (int)(MD / 8));
        gemm256_qkv<<<dim3(4, 64), 512, 0, stream>>>(X, Wb + 2 * WW, ipb + 2 * DM, vtb, 2);
        conv_f2b<<<512, 256, 0, stream>>>(ow, OwB, (int)(WW / 8));
        attn_v4<<<2048, 256, 0, stream>>>(qh, kh, vtb, aout);
        gemm256_out<<<dim3(4, 64), 512, 0, stream>>>(aout, OwB, ob, out);
    } else {
        // Round-1 fallback (needs 100.7 MB, aliases aout onto qkv if tight)
        unsigned short* qkv = (unsigned short*)d_ws;
        const size_t qkv_elems = 3 * MD;
        const size_t need_full = (qkv_elems + MD) * 2;
        unsigned short* aout = (ws_size >= need_full) ? qkv + qkv_elems : qkv;
        gemm_qkv_v1<<<dim3(8, 128, 3), 256, 0, stream>>>(q, k, v, ipw, ipb, qkv);
        attn_win_v1<<<2048, 256, 0, stream>>>(qkv, aout);
        gemm_out_v1<<<dim3(8, 128), 256, 0, stream>>>(aout, ow, ob, out);
    }
}

// Round 8
// 444.243 us; speedup vs baseline: 1.0712x; 1.0338x over previous
//
#include <hip/hip_runtime.h>

// LocalAttention: B=4, L=4096, D=1024, H=16, hd=64, WINDOW=128, nW=32
#define M_TOK 16384
#define DM    1024

typedef __bf16 bf16x8 __attribute__((ext_vector_type(8)));
typedef float  f32x4  __attribute__((ext_vector_type(4)));
typedef unsigned short us8 __attribute__((ext_vector_type(8)));
typedef unsigned short us4 __attribute__((ext_vector_type(4)));

__device__ __forceinline__ unsigned short f2bf(float f) {
    unsigned u = __float_as_uint(f);
    u += 0x7FFFu + ((u >> 16) & 1u);   // RNE
    return (unsigned short)(u >> 16);
}

__device__ __forceinline__ void gl2lds16(const unsigned short* g, unsigned short* l) {
    __builtin_amdgcn_global_load_lds(
        (const __attribute__((address_space(1))) unsigned int*)g,
        (__attribute__((address_space(3))) unsigned int*)l, 16, 0, 0);
}

// ---------------------------------------------------------------------------
// fp32 -> bf16 stream convert, 8 elems/thread
// ---------------------------------------------------------------------------
__global__ __launch_bounds__(256) void conv_f2b(
    const float* __restrict__ src, unsigned short* __restrict__ dst, int n8)
{
    int i = blockIdx.x * blockDim.x + threadIdx.x;
    int stride = gridDim.x * blockDim.x;
    for (; i < n8; i += stride) {
        const float4* s = (const float4*)(src + (size_t)i * 8);
        float4 a = s[0], b = s[1];
        us8 o;
        o[0] = f2bf(a.x); o[1] = f2bf(a.y); o[2] = f2bf(a.z); o[3] = f2bf(a.w);
        o[4] = f2bf(b.x); o[5] = f2bf(b.y); o[6] = f2bf(b.z); o[7] = f2bf(b.w);
        *(us8*)(dst + (size_t)i * 8) = o;
    }
}

// ---------------------------------------------------------------------------
// R4 (kept verbatim, verified): 256x256-tile bf16 NT-GEMM, 512 thr, K split
// into 32 k-halves. LDS = 4-slot ring per matrix (128KB). Stage-issue INSIDE
// the compute phase; counted vmcnt(4); never vmcnt(0) until tail.
// ---------------------------------------------------------------------------
#define STAGE_HALF(x_)                                                       \
    {                                                                        \
        const int s_ = ((x_) & 3) * 8192;                                    \
        _Pragma("unroll")                                                    \
        for (int j = 0; j < 2; ++j) {                                        \
            int p = tid + j * 512;                                           \
            int r = p >> 2, cp = p & 3;                                      \
            int cl = cp ^ ((r >> 1) & 3);                                    \
            gl2lds16(Ab + (size_t)r * DM + (x_) * 32 + cl * 8,               \
                     LA + s_ + p * 8);                                       \
            gl2lds16(Bb + (size_t)r * DM + (x_) * 32 + cl * 8,               \
                     LB + s_ + p * 8);                                       \
        }                                                                    \
    }

#define GEMM256_CORE(A_, B_)                                                 \
    __shared__ unsigned short smem[65536]; /* 128 KB */                      \
    const int tid = threadIdx.x, lane = tid & 63, wv = tid >> 6;             \
    const int wm = wv >> 2, wn = wv & 3;                                     \
    const int lrow = lane & 15, qd = lane >> 4;                              \
    const int orig = blockIdx.y * 4 + blockIdx.x;  /* grid (4,64) = 256 */   \
    const int swz  = (orig & 7) * 32 + (orig >> 3);                          \
    const int mbase = (swz >> 2) * 256, nbase = (swz & 3) * 256;             \
    const unsigned short* Ab = (A_) + (size_t)mbase * DM;                    \
    const unsigned short* Bb = (B_) + (size_t)nbase * DM;                    \
    unsigned short* LA = smem;                                               \
    unsigned short* LB = smem + 32768;                                       \
    const int fsw  = (qd ^ ((lrow >> 1) & 3)) * 8;                           \
    const int aoff = (wm * 128 + lrow) * 32 + fsw;                           \
    const int boff = (wn * 64 + lrow) * 32 + fsw;                            \
    f32x4 acc[8][4] = {};                                                    \
    STAGE_HALF(0)                                                            \
    STAGE_HALF(1)                                                            \
    asm volatile("s_waitcnt vmcnt(4)" ::: "memory");                         \
    __builtin_amdgcn_s_barrier();                                            \
    __builtin_amdgcn_sched_barrier(0);                                       \
    _Pragma("unroll 4")                                                      \
    for (int kh = 0; kh < 32; ++kh) {                                        \
        if (kh < 30) STAGE_HALF(kh + 2)                                      \
        const int sb = (kh & 3) * 8192;                                      \
        bf16x8 af[8], bb[4];                                                 \
        _Pragma("unroll")                                                    \
        for (int mi = 0; mi < 8; ++mi)                                       \
            af[mi] = *(const bf16x8*)(LA + sb + aoff + mi * 512);            \
        _Pragma("unroll")                                                    \
        for (int ni = 0; ni < 4; ++ni)                                       \
            bb[ni] = *(const bf16x8*)(LB + sb + boff + ni * 512);            \
        __builtin_amdgcn_s_setprio(1);                                       \
        _Pragma("unroll")                                                    \
        for (int mi = 0; mi < 8; ++mi)                                       \
            _Pragma("unroll")                                                \
            for (int ni = 0; ni < 4; ++ni)                                   \
                acc[mi][ni] = __builtin_amdgcn_mfma_f32_16x16x32_bf16(       \
                    af[mi], bb[ni], acc[mi][ni], 0, 0, 0);                   \
        __builtin_amdgcn_s_setprio(0);                                       \
        if (kh < 30) { asm volatile("s_waitcnt vmcnt(4)" ::: "memory"); }    \
        else         { asm volatile("s_waitcnt vmcnt(0)" ::: "memory"); }    \
        __builtin_amdgcn_s_barrier();                                        \
        __builtin_amdgcn_sched_barrier(0);                                   \
    }

// GEMM producing attention-friendly layouts:
// z=0/1: C[((b*16+h)*4096 + tok)*64 + dh]   (per-head row-major Q/K)
// z=2  : C[((b*16+h)*64 + dh)*4096 + tok]   (per-head TRANSPOSED V)
__global__ __launch_bounds__(512, 2) void gemm256_qkv(
    const unsigned short* __restrict__ A, const unsigned short* __restrict__ W,
    const float* __restrict__ bias, unsigned short* __restrict__ C, int z)
{
    GEMM256_CORE(A, W)
    if (z <= 1) {
        #pragma unroll
        for (int ni = 0; ni < 4; ++ni) {
            int gc = nbase + wn * 64 + ni * 16 + lrow;
            int h = gc >> 6, dh = gc & 63;
            float bv = bias[gc];
            #pragma unroll
            for (int mi = 0; mi < 8; ++mi) {
                int gr0 = mbase + wm * 128 + mi * 16 + qd * 4;
                int b = gr0 >> 12;
                #pragma unroll
                for (int r = 0; r < 4; ++r) {
                    int tok = (gr0 + r) & 4095;
                    C[(((size_t)b * 16 + h) * 4096 + tok) * 64 + dh] =
                        f2bf(acc[mi][ni][r] + bv);
                }
            }
        }
    } else {
        #pragma unroll
        for (int ni = 0; ni < 4; ++ni) {
            int gc = nbase + wn * 64 + ni * 16 + lrow;
            int h = gc >> 6, dh = gc & 63;
            float bv = bias[gc];
            #pragma unroll
            for (int mi = 0; mi < 8; ++mi) {
                int gr0 = mbase + wm * 128 + mi * 16 + qd * 4;
                int b = gr0 >> 12, tok = gr0 & 4095;
                us4 pk;
                #pragma unroll
                for (int r = 0; r < 4; ++r) pk[r] = f2bf(acc[mi][ni][r] + bv);
                *(us4*)(C + (((size_t)b * 16 + h) * 64 + dh) * 4096 + tok) = pk;
            }
        }
    }
}

__global__ __launch_bounds__(512, 2) void gemm256_out(
    const unsigned short* __restrict__ A, const unsigned short* __restrict__ W,
    const float* __restrict__ bias, float* __restrict__ out)
{
    GEMM256_CORE(A, W)
    #pragma unroll
    for (int ni = 0; ni < 4; ++ni) {
        int gc = nbase + wn * 64 + ni * 16 + lrow;
        float bv = bias[gc];
        #pragma unroll
        for (int mi = 0; mi < 8; ++mi) {
            int gr0 = mbase + wm * 128 + mi * 16 + qd * 4;
            #pragma unroll
            for (int r = 0; r < 4; ++r)
                out[(size_t)(gr0 + r) * DM + gc] = acc[mi][ni][r] + bv;
        }
    }
}

// ---------------------------------------------------------------------------
// Attention v5 (R8): per-wave work IDENTICAL to verified v2, but 1 wave per
// block (8192 blocks x 64 thr). v2's 4 waves never shared LDS data (P rows
// wave-private; K/V loads per-wave duplicated anyway), so the 4-wave block
// was only a residency quantum: 34.8KB LDS -> ~2 blocks/CU resident (23%
// occupancy measured). 1-wave blocks need 8.7KB -> LDS allows 18 blocks/CU,
// VGPR(84) allows 24 waves/CU -> ~18 resident waves to overlap the long
// serial chains. XCD-chunked swizzle keeps the 4 q-slices of one (b,wi,h)
// window on the same XCD so the shared K/V window stays in one L2.
// ---------------------------------------------------------------------------
__global__ __launch_bounds__(64, 4) void attn_v5(
    const unsigned short* __restrict__ qh, const unsigned short* __restrict__ kh,
    const unsigned short* __restrict__ vt, unsigned short* __restrict__ aout)
{
    const int orig = blockIdx.x;                   // 8192
    const int swzb = (orig & 7) * 1024 + (orig >> 3);  // bijective (8192%8==0)
    const int slice = swzb & 3;                    // 32-row q slice
    const int win   = swzb >> 2;                   // (b,wi,h) window
    const int h  = win & 15;
    const int wi = (win >> 4) & 31;
    const int b  = win >> 9;
    const int bh = b * 16 + h;

    const unsigned short* Qp = qh + ((size_t)bh * 4096 + wi * 128 + slice * 32) * 64;
    const unsigned short* Kp = kh + ((size_t)bh * 4096 + wi * 128) * 64;
    const unsigned short* Vp = vt + (size_t)bh * 64 * 4096 + wi * 128;

    const int lane = threadIdx.x & 63;
    const int lrow = lane & 15, qd = lane >> 4, kof = qd * 8;

    __shared__ unsigned short Ps[32 * 136];   // 8.7 KB

    // ---- S = Q K^T ----
    f32x4 acc[2][8] = {};
    #pragma unroll
    for (int ki = 0; ki < 2; ++ki) {
        bf16x8 a0 = *(const bf16x8*)(Qp + ( 0 + lrow) * 64 + ki * 32 + kof);
        bf16x8 a1 = *(const bf16x8*)(Qp + (16 + lrow) * 64 + ki * 32 + kof);
        #pragma unroll
        for (int ni = 0; ni < 8; ++ni) {
            bf16x8 bb = *(const bf16x8*)(Kp + (ni * 16 + lrow) * 64 + ki * 32 + kof);
            acc[0][ni] = __builtin_amdgcn_mfma_f32_16x16x32_bf16(a0, bb, acc[0][ni], 0, 0, 0);
            acc[1][ni] = __builtin_amdgcn_mfma_f32_16x16x32_bf16(a1, bb, acc[1][ni], 0, 0, 0);
        }
    }

    // ---- softmax over the 128 cols (cols live across the 16-lane groups) ----
    const float scale = 0.125f;
    #pragma unroll
    for (int mi = 0; mi < 2; ++mi) {
        #pragma unroll
        for (int r = 0; r < 4; ++r) {
            float sc[8];
            float mx = -3.4e38f;
            #pragma unroll
            for (int ni = 0; ni < 8; ++ni) { sc[ni] = acc[mi][ni][r] * scale; mx = fmaxf(mx, sc[ni]); }
            mx = fmaxf(mx, __shfl_xor(mx, 1));
            mx = fmaxf(mx, __shfl_xor(mx, 2));
            mx = fmaxf(mx, __shfl_xor(mx, 4));
            mx = fmaxf(mx, __shfl_xor(mx, 8));
            float sum = 0.f;
            #pragma unroll
            for (int ni = 0; ni < 8; ++ni) { sc[ni] = __expf(sc[ni] - mx); sum += sc[ni]; }
            sum += __shfl_xor(sum, 1);
            sum += __shfl_xor(sum, 2);
            sum += __shfl_xor(sum, 4);
            sum += __shfl_xor(sum, 8);
            float inv = 1.0f / sum;
            #pragma unroll
            for (int ni = 0; ni < 8; ++ni) acc[mi][ni][r] = sc[ni] * inv;
        }
    }

    // ---- P to LDS (single wave; no barrier needed) ----
    #pragma unroll
    for (int mi = 0; mi < 2; ++mi)
        #pragma unroll
        for (int ni = 0; ni < 8; ++ni)
            #pragma unroll
            for (int r = 0; r < 4; ++r)
                Ps[(mi * 16 + qd * 4 + r) * 136 + ni * 16 + lrow] =
                    f2bf(acc[mi][ni][r]);

    // ---- O = P V (V fragments direct from global transposed layout) ----
    f32x4 o[2][4] = {};
    #pragma unroll
    for (int kj = 0; kj < 4; ++kj) {
        bf16x8 a0 = *(const bf16x8*)(Ps + ( 0 + lrow) * 136 + kj * 32 + kof);
        bf16x8 a1 = *(const bf16x8*)(Ps + (16 + lrow) * 136 + kj * 32 + kof);
        #pragma unroll
        for (int nd = 0; nd < 4; ++nd) {
            bf16x8 bb = *(const bf16x8*)(Vp + (size_t)(nd * 16 + lrow) * 4096 + kj * 32 + kof);
            o[0][nd] = __builtin_amdgcn_mfma_f32_16x16x32_bf16(a0, bb, o[0][nd], 0, 0, 0);
            o[1][nd] = __builtin_amdgcn_mfma_f32_16x16x32_bf16(a1, bb, o[1][nd], 0, 0, 0);
        }
    }

    // ---- write row-major [M][1024] bf16 for the out-projection GEMM ----
    #pragma unroll
    for (int mi = 0; mi < 2; ++mi)
        #pragma unroll
        for (int nd = 0; nd < 4; ++nd)
            #pragma unroll
            for (int r = 0; r < 4; ++r) {
                int R = slice * 32 + mi * 16 + qd * 4 + r;
                int c = h * 64 + nd * 16 + lrow;
                aout[(size_t)(b * 4096 + wi * 128 + R) * DM + c] = f2bf(o[mi][nd][r]);
            }
}

// ===========================================================================
// Round-1 fallback pipeline (used only if ws_size is too small for the bf16
// pre-convert layout). Verified correct in Round 1.
// ===========================================================================
__global__ __launch_bounds__(256) void gemm_qkv_v1(
    const float* __restrict__ qin, const float* __restrict__ kin,
    const float* __restrict__ vin, const float* __restrict__ ipw,
    const float* __restrict__ ipb, unsigned short* __restrict__ qkv)
{
    __shared__ unsigned short As[128 * 40];
    __shared__ unsigned short Ws[128 * 40];
    const int z = blockIdx.z;
    const float* A  = (z == 0) ? qin : ((z == 1) ? kin : vin);
    const float* Wp = ipw + (size_t)z * DM * DM;
    const float* bp = ipb + z * DM;
    unsigned short* Cp = qkv + (size_t)z * M_TOK * DM;
    const int mbase = blockIdx.y * 128, nbase = blockIdx.x * 128;
    const int tid = threadIdx.x, lane = tid & 63, wv = tid >> 6;
    const int wrow = (wv >> 1) * 64, wcol = (wv & 1) * 64;
    const int lrow = lane & 15, kof = (lane >> 4) * 8;
    const int srow = tid >> 3, sc4 = tid & 7;
    f32x4 acc[4][4] = {};
    for (int ks = 0; ks < 32; ++ks) {
        const int k0 = ks * 32;
        __syncthreads();
        #pragma unroll
        for (int it = 0; it < 4; ++it) {
            int row = it * 32 + srow;
            float4 av = *(const float4*)(A  + (size_t)(mbase + row) * DM + k0 + sc4 * 4);
            float4 wf = *(const float4*)(Wp + (size_t)(nbase + row) * DM + k0 + sc4 * 4);
            us4 ap, wp4;
            ap[0] = f2bf(av.x); ap[1] = f2bf(av.y); ap[2] = f2bf(av.z); ap[3] = f2bf(av.w);
            wp4[0] = f2bf(wf.x); wp4[1] = f2bf(wf.y); wp4[2] = f2bf(wf.z); wp4[3] = f2bf(wf.w);
            *(us4*)(As + row * 40 + sc4 * 4) = ap;
            *(us4*)(Ws + row * 40 + sc4 * 4) = wp4;
        }
        __syncthreads();
        bf16x8 af[4], bfr[4];
        #pragma unroll
        for (int i = 0; i < 4; ++i) af[i]  = *(const bf16x8*)(As + (wrow + i * 16 + lrow) * 40 + kof);
        #pragma unroll
        for (int i = 0; i < 4; ++i) bfr[i] = *(const bf16x8*)(Ws + (wcol + i * 16 + lrow) * 40 + kof);
        #pragma unroll
        for (int i = 0; i < 4; ++i)
            #pragma unroll
            for (int j = 0; j < 4; ++j)
                acc[i][j] = __builtin_amdgcn_mfma_f32_16x16x32_bf16(af[i], bfr[j], acc[i][j], 0, 0, 0);
    }
    #pragma unroll
    for (int j = 0; j < 4; ++j) {
        int gc = nbase + wcol + j * 16 + lrow;
        float bv = bp[gc];
        #pragma unroll
        for (int i = 0; i < 4; ++i) {
            int gr0 = mbase + wrow + i * 16 + (lane >> 4) * 4;
            #pragma unroll
            for (int r = 0; r < 4; ++r)
                Cp[(size_t)(gr0 + r) * DM + gc] = f2bf(acc[i][j][r] + bv);
        }
    }
}

__global__ __launch_bounds__(256) void gemm_out_v1(
    const unsigned short* __restrict__ x, const float* __restrict__ ow,
    const float* __restrict__ ob, float* __restrict__ out)
{
    __shared__ unsigned short As[128 * 40];
    __shared__ unsigned short Ws[128 * 40];
    const int mbase = blockIdx.y * 128, nbase = blockIdx.x * 128;
    const int tid = threadIdx.x, lane = tid & 63, wv = tid >> 6;
    const int wrow = (wv >> 1) * 64, wcol = (wv & 1) * 64;
    const int lrow = lane & 15, kof = (lane >> 4) * 8;
    const int srow = tid >> 3, sc4 = tid & 7;
    f32x4 acc[4][4] = {};
    for (int ks = 0; ks < 32; ++ks) {
        const int k0 = ks * 32;
        __syncthreads();
        #pragma unroll
        for (int it = 0; it < 4; ++it) {
            int row = it * 32 + srow;
            us4 av = *(const us4*)(x + (size_t)(mbase + row) * DM + k0 + sc4 * 4);
            float4 wf = *(const float4*)(ow + (size_t)(nbase + row) * DM + k0 + sc4 * 4);
            us4 wp4;
            wp4[0] = f2bf(wf.x); wp4[1] = f2bf(wf.y); wp4[2] = f2bf(wf.z); wp4[3] = f2bf(wf.w);
            *(us4*)(As + row * 40 + sc4 * 4) = av;
            *(us4*)(Ws + row * 40 + sc4 * 4) = wp4;
        }
        __syncthreads();
        bf16x8 af[4], bfr[4];
        #pragma unroll
        for (int i = 0; i < 4; ++i) af[i]  = *(const bf16x8*)(As + (wrow + i * 16 + lrow) * 40 + kof);
        #pragma unroll
        for (int i = 0; i < 4; ++i) bfr[i] = *(const bf16x8*)(Ws + (wcol + i * 16 + lrow) * 40 + kof);
        #pragma unroll
        for (int i = 0; i < 4; ++i)
            #pragma unroll
            for (int j = 0; j < 4; ++j)
                acc[i][j] = __builtin_amdgcn_mfma_f32_16x16x32_bf16(af[i], bfr[j], acc[i][j], 0, 0, 0);
    }
    #pragma unroll
    for (int j = 0; j < 4; ++j) {
        int gc = nbase + wcol + j * 16 + lrow;
        float bv = ob[gc];
        #pragma unroll
        for (int i = 0; i < 4; ++i) {
            int gr0 = mbase + wrow + i * 16 + (lane >> 4) * 4;
            #pragma unroll
            for (int r = 0; r < 4; ++r)
                out[(size_t)(gr0 + r) * DM + gc] = acc[i][j][r] + bv;
        }
    }
}

__global__ __launch_bounds__(256) void attn_win_v1(
    const unsigned short* __restrict__ qkv, unsigned short* __restrict__ aout)
{
    const unsigned short* qp = qkv;
    const unsigned short* kp = qkv + (size_t)M_TOK * DM;
    const unsigned short* vp = qkv + 2 * (size_t)M_TOK * DM;
    const int gid = blockIdx.x;
    const int h = gid & 15, wi = (gid >> 4) & 31, b = gid >> 9;
    const size_t rowbase = (size_t)b * 4096 + (size_t)wi * 128;
    const int tid = threadIdx.x, lane = tid & 63, wv = tid >> 6;
    const int lrow = lane & 15, kof = (lane >> 4) * 8;
    __shared__ unsigned short sm[27136];
    unsigned short* Qs = sm;
    unsigned short* Ks = sm + 9216;
    unsigned short* Vt = sm + 18432;
    unsigned short* Ps = sm;
    {
        const int seg = tid & 7;
        #pragma unroll
        for (int it = 0; it < 4; ++it) {
            int r = it * 32 + (tid >> 3);
            size_t g = (rowbase + r) * DM + h * 64 + seg * 8;
            *(int4*)(Qs + r * 72 + seg * 8) = *(const int4*)(qp + g);
            *(int4*)(Ks + r * 72 + seg * 8) = *(const int4*)(kp + g);
        }
        #pragma unroll
        for (int it = 0; it < 4; ++it) {
            int j = tid & 127;
            int sg = it * 2 + (tid >> 7);
            us8 vv = *(const us8*)(vp + (rowbase + j) * DM + h * 64 + sg * 8);
            #pragma unroll
            for (int d = 0; d < 8; ++d) Vt[(sg * 8 + d) * 136 + j] = vv[d];
        }
    }
    __syncthreads();
    f32x4 acc[2][8] = {};
    #pragma unroll
    for (int ki = 0; ki < 2; ++ki) {
        bf16x8 a0 = *(const bf16x8*)(Qs + (wv * 32 +  0 + lrow) * 72 + ki * 32 + kof);
        bf16x8 a1 = *(const bf16x8*)(Qs + (wv * 32 + 16 + lrow) * 72 + ki * 32 + kof);
        #pragma unroll
        for (int ni = 0; ni < 8; ++ni) {
            bf16x8 bb = *(const bf16x8*)(Ks + (ni * 16 + lrow) * 72 + ki * 32 + kof);
            acc[0][ni] = __builtin_amdgcn_mfma_f32_16x16x32_bf16(a0, bb, acc[0][ni], 0, 0, 0);
            acc[1][ni] = __builtin_amdgcn_mfma_f32_16x16x32_bf16(a1, bb, acc[1][ni], 0, 0, 0);
        }
    }
    const float scale = 0.125f;
    #pragma unroll
    for (int mi = 0; mi < 2; ++mi) {
        #pragma unroll
        for (int r = 0; r < 4; ++r) {
            float sc[8];
            float mx = -3.4e38f;
            #pragma unroll
            for (int ni = 0; ni < 8; ++ni) { sc[ni] = acc[mi][ni][r] * scale; mx = fmaxf(mx, sc[ni]); }
            mx = fmaxf(mx, __shfl_xor(mx, 1)); mx = fmaxf(mx, __shfl_xor(mx, 2));
            mx = fmaxf(mx, __shfl_xor(mx, 4)); mx = fmaxf(mx, __shfl_xor(mx, 8));
            float sum = 0.f;
            #pragma unroll
            for (int ni = 0; ni < 8; ++ni) { sc[ni] = __expf(sc[ni] - mx); sum += sc[ni]; }
            sum += __shfl_xor(sum, 1); sum += __shfl_xor(sum, 2);
            sum += __shfl_xor(sum, 4); sum += __shfl_xor(sum, 8);
            float inv = 1.0f / sum;
            #pragma unroll
            for (int ni = 0; ni < 8; ++ni) acc[mi][ni][r] = sc[ni] * inv;
        }
    }
    __syncthreads();
    #pragma unroll
    for (int mi = 0; mi < 2; ++mi)
        #pragma unroll
        for (int ni = 0; ni < 8; ++ni)
            #pragma unroll
            for (int r = 0; r < 4; ++r)
                Ps[(wv * 32 + mi * 16 + (lane >> 4) * 4 + r) * 136 + ni * 16 + lrow] =
                    f2bf(acc[mi][ni][r]);
    __syncthreads();
    f32x4 o[2][4] = {};
    #pragma unroll
    for (int kj = 0; kj < 4; ++kj) {
        bf16x8 a0 = *(const bf16x8*)(Ps + (wv * 32 +  0 + lrow) * 136 + kj * 32 + kof);
        bf16x8 a1 = *(const bf16x8*)(Ps + (wv * 32 + 16 + lrow) * 136 + kj * 32 + kof);
        #pragma unroll
        for (int nd = 0; nd < 4; ++nd) {
            bf16x8 bb = *(const bf16x8*)(Vt + (nd * 16 + lrow) * 136 + kj * 32 + kof);
            o[0][nd] = __builtin_amdgcn_mfma_f32_16x16x32_bf16(a0, bb, o[0][nd], 0, 0, 0);
            o[1][nd] = __builtin_amdgcn_mfma_f32_16x16x32_bf16(a1, bb, o[1][nd], 0, 0, 0);
        }
    }
    #pragma unroll
    for (int mi = 0; mi < 2; ++mi)
        #pragma unroll
        for (int nd = 0; nd < 4; ++nd)
            #pragma unroll
            for (int r = 0; r < 4; ++r) {
                int R = wv * 32 + mi * 16 + (lane >> 4) * 4 + r;
                int c = h * 64 + nd * 16 + lrow;
                aout[(rowbase + R) * DM + c] = f2bf(o[mi][nd][r]);
            }
}

// ---------------------------------------------------------------------------
extern "C" void kernel_launch(void* const* d_in, const int* in_sizes, int n_in,
                              void* d_out, int out_size, void* d_ws, size_t ws_size,
                              hipStream_t stream) {
    const float* q   = (const float*)d_in[0];
    const float* k   = (const float*)d_in[1];
    const float* v   = (const float*)d_in[2];
    const float* ipw = (const float*)d_in[3];
    const float* ipb = (const float*)d_in[4];
    const float* ow  = (const float*)d_in[5];
    const float* ob  = (const float*)d_in[6];
    float* out = (float*)d_out;

    const size_t MD = (size_t)M_TOK * DM;          // 16,777,216 elems
    const size_t WW = (size_t)DM * DM;             // 1,048,576 elems
    const size_t need = (4 * MD + 3 * WW) * 2;     // 140,509,184 B

    if (ws_size >= need) {
        unsigned short* X   = (unsigned short*)d_ws;       // one fp32->bf16 slot
        unsigned short* qh  = X + MD;
        unsigned short* kh  = X + 2 * MD;
        unsigned short* vtb = X + 3 * MD;
        unsigned short* Wb  = X + 4 * MD;                  // 3 weight mats bf16
        unsigned short* aout = X;                          // alias (X dead after gemms)
        unsigned short* OwB  = Wb;                         // alias (Wb dead after gemms)

        conv_f2b<<<1536, 256, 0, stream>>>(ipw, Wb, (int)(3 * WW / 8));
        conv_f2b<<<8192, 256, 0, stream>>>(q, X, (int)(MD / 8));
        gemm256_qkv<<<dim3(4, 64), 512, 0, stream>>>(X, Wb, ipb, qh, 0);
        conv_f2b<<<8192, 256, 0, stream>>>(k, X, (int)(MD / 8));
        gemm256_qkv<<<dim3(4, 64), 512, 0, stream>>>(X, Wb + WW, ipb + DM, kh, 1);
        conv_f2b<<<8192, 256, 0, stream>>>(v, X, (int)(MD / 8));
        gemm256_qkv<<<dim3(4, 64), 512, 0, stream>>>(X, Wb + 2 * WW, ipb + 2 * DM, vtb, 2);
        conv_f2b<<<512, 256, 0, stream>>>(ow, OwB, (int)(WW / 8));
        attn_v5<<<8192, 64, 0, stream>>>(qh, kh, vtb, aout);
        gemm256_out<<<dim3(4, 64), 512, 0, stream>>>(aout, OwB, ob, out);
    } else {
        // Round-1 fallback (needs 100.7 MB, aliases aout onto qkv if tight)
        unsigned short* qkv = (unsigned short*)d_ws;
        const size_t qkv_elems = 3 * MD;
        const size_t need_full = (qkv_elems + MD) * 2;
        unsigned short* aout = (ws_size >= need_full) ? qkv + qkv_elems : qkv;
        gemm_qkv_v1<<<dim3(8, 128, 3), 256, 0, stream>>>(q, k, v, ipw, ipb, qkv);
        attn_win_v1<<<2048, 256, 0, stream>>>(qkv, aout);
        gemm_out_v1<<<dim3(8, 128), 256, 0, stream>>>(aout, ow, ob, out);
    }
}